// Round 7
// baseline (24638.051 us; speedup 1.0000x reference)
//
#include <hip/hip_runtime.h>

// Residual VQ — np-f32 bit-faithful. Round 7: DS=8 -> LDS ~67 KB -> 2
// blocks/CU (16 waves) so staging stalls / barrier drains / per-level serial
// phases overlap across blocks. Numerics byte-identical to round-6 PASS.
//
// Frozen numerics (validated round 4/6):
//   dot:   single sequential fmaf chain over d=0..255 ascending per (tok,k)
//   A,C:   np pairwise-sum-of-squares (AVX512 tree) replica
//   dist:  fl(fl(A - fl(2*dot)) + C), argmin strict-<, first-index ties
//   resid: r = fl(r - c[idx]) elementwise
//
// Org: block = 32 tokens, 512 threads = 8 waves. Wave w owns k in
// [128w, 128w+128). Lane grid 4 tg x 16 kg; per lane 8 tokens (tg+4i) x
// 8 k (128w+kg+16j), acc[8][8] persists over 32 d-slices of 8.
// LDS: r_m[32][260] row-major, c_s[1024*8] with float4-slot swizzle
// part ^ ((k>>2)&1)  (uniform bank tiling on write, 2-way on read).

#define NTOK 131072
#define DEPTH 8
#define KCB 1024
#define DIM 256
#define TM 32
#define DS 8
#define NSLICE (DIM / DS)
#define RP 260

__device__ __forceinline__ float np_sumsq_128(const float* p) {
  float s[16];
#pragma unroll
  for (int l = 0; l < 16; ++l) {
    float r0 = __fadd_rn(__fmul_rn(p[l], p[l]),
                         __fmul_rn(p[l + 64], p[l + 64]));
    float r1 = __fadd_rn(__fmul_rn(p[l + 16], p[l + 16]),
                         __fmul_rn(p[l + 80], p[l + 80]));
    float r2 = __fadd_rn(__fmul_rn(p[l + 32], p[l + 32]),
                         __fmul_rn(p[l + 96], p[l + 96]));
    float r3 = __fadd_rn(__fmul_rn(p[l + 48], p[l + 48]),
                         __fmul_rn(p[l + 112], p[l + 112]));
    s[l] = __fadd_rn(__fadd_rn(r0, r1), __fadd_rn(r2, r3));
  }
  float t[8];
#pragma unroll
  for (int l = 0; l < 8; ++l) t[l] = __fadd_rn(s[l], s[l + 8]);
  float u[4];
#pragma unroll
  for (int l = 0; l < 4; ++l) u[l] = __fadd_rn(t[l], t[l + 4]);
  return __fadd_rn(__fadd_rn(u[0], u[2]), __fadd_rn(u[1], u[3]));
}

__device__ __forceinline__ float np_sumsq_256(const float* p) {
  return __fadd_rn(np_sumsq_128(p), np_sumsq_128(p + 128));
}

__global__ __launch_bounds__(256) void c2_kernel(const float* __restrict__ cbs,
                                                 float* __restrict__ C32g) {
  int gid = blockIdx.x * 256 + threadIdx.x;
  C32g[gid] = np_sumsq_256(cbs + (size_t)gid * DIM);
}

__global__ __launch_bounds__(512, 4) void rvq_kernel(
    const float* __restrict__ latent, const float* __restrict__ cbs,
    const float* __restrict__ C32g, float* __restrict__ out) {
  __shared__ float r_m[TM][RP];
  __shared__ float c_s[KCB * DS];
  __shared__ float A_s[TM];
  __shared__ float best_s[8][TM];
  __shared__ int bidx_s[8][TM];
  __shared__ int idx_s[TM];

  const int tid = threadIdx.x;
  const int w = tid >> 6;
  const int lane = tid & 63;
  const int tg = lane >> 4;
  const int kg = lane & 15;
  const int n0 = blockIdx.x * TM;

  // ---- stage latent -> r_m (exact copy) ----
  {
    int tok = tid >> 4;
    int db = (tid & 15) * 16;
    const float* src = latent + (size_t)(n0 + tok) * DIM + db;
#pragma unroll
    for (int j = 0; j < 4; ++j)
      *(float4*)&r_m[tok][db + j * 4] = *(const float4*)(src + j * 4);
  }
  __syncthreads();

  const int kbase = w * 128 + kg;   // lane's k_j = kbase + 16*j
  const int swz = (kbase >> 2) & 1; // j-invariant ((16j)>>2 is even)

  for (int lvl = 0; lvl < DEPTH; ++lvl) {
    const float* cb = cbs + (size_t)lvl * KCB * DIM;
    if (tid < TM) A_s[tid] = np_sumsq_256(&r_m[tid][0]);

    float acc[8][8];
#pragma unroll
    for (int i = 0; i < 8; ++i)
#pragma unroll
      for (int j = 0; j < 8; ++j) acc[i][j] = 0.f;

    for (int ds = 0; ds < NSLICE; ++ds) {
      __syncthreads();  // prev slice reads done (and A_s ordered at ds=0)
      // ---- stage c-slice [1024 k][8 d]: 2048 float4 slots / 512 thr = 4 ----
      {
        const int d0 = ds * DS;
        const int part = tid & 1;
#pragma unroll
        for (int g = 0; g < 4; ++g) {
          int k = g * 256 + (tid >> 1);
          float4 v = *(const float4*)(cb + (size_t)k * DIM + d0 + part * 4);
          int p2 = part ^ ((k >> 2) & 1);
          *(float4*)&c_s[k * 8 + p2 * 4] = v;
        }
      }
      __syncthreads();

      // ---- 2 substeps of 4 d-values each; chain strictly d-ascending ----
#pragma unroll
      for (int sub = 0; sub < 2; ++sub) {
        float4 rv[8], cv[8];
        const int rd = ds * DS + sub * 4;
#pragma unroll
        for (int i = 0; i < 8; ++i)
          rv[i] = *(const float4*)&r_m[tg + 4 * i][rd];
        const int csub = (sub ^ swz) << 2;
#pragma unroll
        for (int j = 0; j < 8; ++j)
          cv[j] = *(const float4*)&c_s[(kbase + 16 * j) * 8 + csub];
#pragma unroll
        for (int i = 0; i < 8; ++i)
#pragma unroll
          for (int j = 0; j < 8; ++j) {
            float a = acc[i][j];
            a = fmaf(rv[i].x, cv[j].x, a);
            a = fmaf(rv[i].y, cv[j].y, a);
            a = fmaf(rv[i].z, cv[j].z, a);
            a = fmaf(rv[i].w, cv[j].w, a);
            acc[i][j] = a;
          }
      }
    }

    // ---- dist combine + per-lane argmin (j ascending = k ascending) ----
    float bv[8];
    int bk[8];
#pragma unroll
    for (int i = 0; i < 8; ++i) {
      bv[i] = 3.4e38f;
      bk[i] = 0;
    }
#pragma unroll
    for (int j = 0; j < 8; ++j) {
      const int k = kbase + 16 * j;
      const float C = C32g[lvl * KCB + k];
#pragma unroll
      for (int i = 0; i < 8; ++i) {
        float d = __fadd_rn(
            __fsub_rn(A_s[tg + 4 * i], __fmul_rn(2.0f, acc[i][j])), C);
        if (d < bv[i]) {
          bv[i] = d;
          bk[i] = k;
        }
      }
    }

    // ---- butterfly over the 16 kg lanes (index tie-break) ----
#pragma unroll
    for (int m = 1; m <= 8; m <<= 1) {
#pragma unroll
      for (int i = 0; i < 8; ++i) {
        float ov = __shfl_xor(bv[i], m);
        int ok = __shfl_xor(bk[i], m);
        if (ov < bv[i] || (ov == bv[i] && ok < bk[i])) {
          bv[i] = ov;
          bk[i] = ok;
        }
      }
    }
    if (kg == 0) {
#pragma unroll
      for (int i = 0; i < 8; ++i) {
        best_s[w][tg + 4 * i] = bv[i];
        bidx_s[w][tg + 4 * i] = bk[i];
      }
    }
    __syncthreads();

    // ---- cross-wave merge (w ascending = k ascending; strict <) ----
    if (tid < TM) {
      float b = best_s[0][tid];
      int k = bidx_s[0][tid];
#pragma unroll
      for (int ww = 1; ww < 8; ++ww) {
        float ov = best_s[ww][tid];
        int ok = bidx_s[ww][tid];
        if (ov < b || (ov == b && ok < k)) {
          b = ov;
          k = ok;
        }
      }
      idx_s[tid] = k;
      out[(size_t)NTOK * DIM + (size_t)lvl * NTOK + n0 + tid] = (float)k;
    }
    __syncthreads();

    // ---- residual update: r = fl(r - c[idx]) elementwise ----
    {
      int tok = tid >> 4;
      int db = (tid & 15) * 16;
      const float* crow = cb + (size_t)idx_s[tok] * DIM + db;
#pragma unroll
      for (int j = 0; j < 4; ++j) {
        float4 cv4 = *(const float4*)(crow + j * 4);
        int d = db + j * 4;
        r_m[tok][d + 0] = __fsub_rn(r_m[tok][d + 0], cv4.x);
        r_m[tok][d + 1] = __fsub_rn(r_m[tok][d + 1], cv4.y);
        r_m[tok][d + 2] = __fsub_rn(r_m[tok][d + 2], cv4.z);
        r_m[tok][d + 3] = __fsub_rn(r_m[tok][d + 3], cv4.w);
      }
    }
    __syncthreads();  // r stable before next level's A
  }

  // ---- straight_through = fl(l + fl(q - l)), q = fl(l - r) ----
  {
    int tok = tid >> 4;
    int db = (tid & 15) * 16;
#pragma unroll
    for (int j = 0; j < 4; ++j) {
      int d = db + j * 4;
      size_t gi = (size_t)(n0 + tok) * DIM + d;
      float4 l4 = *(const float4*)(latent + gi);
      float4 qv;
      float q;
      q = __fsub_rn(l4.x, r_m[tok][d + 0]);
      qv.x = __fadd_rn(l4.x, __fsub_rn(q, l4.x));
      q = __fsub_rn(l4.y, r_m[tok][d + 1]);
      qv.y = __fadd_rn(l4.y, __fsub_rn(q, l4.y));
      q = __fsub_rn(l4.z, r_m[tok][d + 2]);
      qv.z = __fadd_rn(l4.z, __fsub_rn(q, l4.z));
      q = __fsub_rn(l4.w, r_m[tok][d + 3]);
      qv.w = __fadd_rn(l4.w, __fsub_rn(q, l4.w));
      *(float4*)(out + gi) = qv;
    }
  }
}

extern "C" void kernel_launch(void* const* d_in, const int* in_sizes, int n_in,
                              void* d_out, int out_size, void* d_ws,
                              size_t ws_size, hipStream_t stream) {
  const float* latent = (const float*)d_in[0];
  const float* codebooks = (const float*)d_in[1];
  float* out = (float*)d_out;
  float* C32g = (float*)d_ws;  // 8192 floats

  hipLaunchKernelGGL(c2_kernel, dim3(DEPTH * KCB / 256), dim3(256), 0, stream,
                     codebooks, C32g);
  hipLaunchKernelGGL(rvq_kernel, dim3(NTOK / TM), dim3(512), 0, stream, latent,
                     codebooks, C32g, out);
}

// Round 8
// 10845.882 us; speedup vs baseline: 2.2717x; 2.2717x over previous
//
#include <hip/hip_runtime.h>

// Residual VQ — np-f32 bit-faithful. Round 8: fix the round-7 spill.
// launch_bounds 2nd arg is empirically CUDA-style min-BLOCKS/CU on hipcc:
// (512,4) capped VGPR at 64 -> acc[8][8] spilled -> 100 GB scratch traffic.
// (512,2) -> 2 blocks/CU, VGPR cap 128 (round-6's natural, spill-free count).
// Numerics byte-identical to round-6/7 PASS.
//
// Frozen numerics (validated round 4/6/7):
//   dot:   single sequential fmaf chain over d=0..255 ascending per (tok,k)
//   A,C:   np pairwise-sum-of-squares (AVX512 tree) replica
//   dist:  fl(fl(A - fl(2*dot)) + C), argmin strict-<, first-index ties
//   resid: r = fl(r - c[idx]) elementwise
//
// Org: block = 32 tokens, 512 threads = 8 waves. Wave w owns k in
// [128w, 128w+128). Lane grid 4 tg x 16 kg; per lane 8 tokens (tg+4i) x
// 8 k (128w+kg+16j), acc[8][8] persists over 32 d-slices of 8.
// LDS (~68 KB): r_m[32][260] row-major, c_s[1024*8] with float4-slot
// swizzle part ^ ((k>>2)&1).

#define NTOK 131072
#define DEPTH 8
#define KCB 1024
#define DIM 256
#define TM 32
#define DS 8
#define NSLICE (DIM / DS)
#define RP 260

__device__ __forceinline__ float np_sumsq_128(const float* p) {
  float s[16];
#pragma unroll
  for (int l = 0; l < 16; ++l) {
    float r0 = __fadd_rn(__fmul_rn(p[l], p[l]),
                         __fmul_rn(p[l + 64], p[l + 64]));
    float r1 = __fadd_rn(__fmul_rn(p[l + 16], p[l + 16]),
                         __fmul_rn(p[l + 80], p[l + 80]));
    float r2 = __fadd_rn(__fmul_rn(p[l + 32], p[l + 32]),
                         __fmul_rn(p[l + 96], p[l + 96]));
    float r3 = __fadd_rn(__fmul_rn(p[l + 48], p[l + 48]),
                         __fmul_rn(p[l + 112], p[l + 112]));
    s[l] = __fadd_rn(__fadd_rn(r0, r1), __fadd_rn(r2, r3));
  }
  float t[8];
#pragma unroll
  for (int l = 0; l < 8; ++l) t[l] = __fadd_rn(s[l], s[l + 8]);
  float u[4];
#pragma unroll
  for (int l = 0; l < 4; ++l) u[l] = __fadd_rn(t[l], t[l + 4]);
  return __fadd_rn(__fadd_rn(u[0], u[2]), __fadd_rn(u[1], u[3]));
}

__device__ __forceinline__ float np_sumsq_256(const float* p) {
  return __fadd_rn(np_sumsq_128(p), np_sumsq_128(p + 128));
}

__global__ __launch_bounds__(256) void c2_kernel(const float* __restrict__ cbs,
                                                 float* __restrict__ C32g) {
  int gid = blockIdx.x * 256 + threadIdx.x;
  C32g[gid] = np_sumsq_256(cbs + (size_t)gid * DIM);
}

__global__ __launch_bounds__(512, 2) void rvq_kernel(
    const float* __restrict__ latent, const float* __restrict__ cbs,
    const float* __restrict__ C32g, float* __restrict__ out) {
  __shared__ float r_m[TM][RP];
  __shared__ float c_s[KCB * DS];
  __shared__ float A_s[TM];
  __shared__ float best_s[8][TM];
  __shared__ int bidx_s[8][TM];
  __shared__ int idx_s[TM];

  const int tid = threadIdx.x;
  const int w = tid >> 6;
  const int lane = tid & 63;
  const int tg = lane >> 4;
  const int kg = lane & 15;
  const int n0 = blockIdx.x * TM;

  // ---- stage latent -> r_m (exact copy) ----
  {
    int tok = tid >> 4;
    int db = (tid & 15) * 16;
    const float* src = latent + (size_t)(n0 + tok) * DIM + db;
#pragma unroll
    for (int j = 0; j < 4; ++j)
      *(float4*)&r_m[tok][db + j * 4] = *(const float4*)(src + j * 4);
  }
  __syncthreads();

  const int kbase = w * 128 + kg;   // lane's k_j = kbase + 16*j
  const int swz = (kbase >> 2) & 1; // j-invariant ((16j)>>2 is even)

  for (int lvl = 0; lvl < DEPTH; ++lvl) {
    const float* cb = cbs + (size_t)lvl * KCB * DIM;
    if (tid < TM) A_s[tid] = np_sumsq_256(&r_m[tid][0]);

    float acc[8][8];
#pragma unroll
    for (int i = 0; i < 8; ++i)
#pragma unroll
      for (int j = 0; j < 8; ++j) acc[i][j] = 0.f;

    for (int ds = 0; ds < NSLICE; ++ds) {
      __syncthreads();  // prev slice reads done (and A_s ordered at ds=0)
      // ---- stage c-slice [1024 k][8 d]: 2048 float4 slots / 512 thr = 4 ----
      {
        const int d0 = ds * DS;
        const int part = tid & 1;
#pragma unroll
        for (int g = 0; g < 4; ++g) {
          int k = g * 256 + (tid >> 1);
          float4 v = *(const float4*)(cb + (size_t)k * DIM + d0 + part * 4);
          int p2 = part ^ ((k >> 2) & 1);
          *(float4*)&c_s[k * 8 + p2 * 4] = v;
        }
      }
      __syncthreads();

      // ---- 2 substeps of 4 d-values each; chain strictly d-ascending ----
#pragma unroll
      for (int sub = 0; sub < 2; ++sub) {
        float4 rv[8], cv[8];
        const int rd = ds * DS + sub * 4;
#pragma unroll
        for (int i = 0; i < 8; ++i)
          rv[i] = *(const float4*)&r_m[tg + 4 * i][rd];
        const int csub = (sub ^ swz) << 2;
#pragma unroll
        for (int j = 0; j < 8; ++j)
          cv[j] = *(const float4*)&c_s[(kbase + 16 * j) * 8 + csub];
#pragma unroll
        for (int i = 0; i < 8; ++i)
#pragma unroll
          for (int j = 0; j < 8; ++j) {
            float a = acc[i][j];
            a = fmaf(rv[i].x, cv[j].x, a);
            a = fmaf(rv[i].y, cv[j].y, a);
            a = fmaf(rv[i].z, cv[j].z, a);
            a = fmaf(rv[i].w, cv[j].w, a);
            acc[i][j] = a;
          }
      }
    }

    // ---- dist combine + per-lane argmin (j ascending = k ascending) ----
    float bv[8];
    int bk[8];
#pragma unroll
    for (int i = 0; i < 8; ++i) {
      bv[i] = 3.4e38f;
      bk[i] = 0;
    }
#pragma unroll
    for (int j = 0; j < 8; ++j) {
      const int k = kbase + 16 * j;
      const float C = C32g[lvl * KCB + k];
#pragma unroll
      for (int i = 0; i < 8; ++i) {
        float d = __fadd_rn(
            __fsub_rn(A_s[tg + 4 * i], __fmul_rn(2.0f, acc[i][j])), C);
        if (d < bv[i]) {
          bv[i] = d;
          bk[i] = k;
        }
      }
    }

    // ---- butterfly over the 16 kg lanes (index tie-break) ----
#pragma unroll
    for (int m = 1; m <= 8; m <<= 1) {
#pragma unroll
      for (int i = 0; i < 8; ++i) {
        float ov = __shfl_xor(bv[i], m);
        int ok = __shfl_xor(bk[i], m);
        if (ov < bv[i] || (ov == bv[i] && ok < bk[i])) {
          bv[i] = ov;
          bk[i] = ok;
        }
      }
    }
    if (kg == 0) {
#pragma unroll
      for (int i = 0; i < 8; ++i) {
        best_s[w][tg + 4 * i] = bv[i];
        bidx_s[w][tg + 4 * i] = bk[i];
      }
    }
    __syncthreads();

    // ---- cross-wave merge (w ascending = k ascending; strict <) ----
    if (tid < TM) {
      float b = best_s[0][tid];
      int k = bidx_s[0][tid];
#pragma unroll
      for (int ww = 1; ww < 8; ++ww) {
        float ov = best_s[ww][tid];
        int ok = bidx_s[ww][tid];
        if (ov < b || (ov == b && ok < k)) {
          b = ov;
          k = ok;
        }
      }
      idx_s[tid] = k;
      out[(size_t)NTOK * DIM + (size_t)lvl * NTOK + n0 + tid] = (float)k;
    }
    __syncthreads();

    // ---- residual update: r = fl(r - c[idx]) elementwise ----
    {
      int tok = tid >> 4;
      int db = (tid & 15) * 16;
      const float* crow = cb + (size_t)idx_s[tok] * DIM + db;
#pragma unroll
      for (int j = 0; j < 4; ++j) {
        float4 cv4 = *(const float4*)(crow + j * 4);
        int d = db + j * 4;
        r_m[tok][d + 0] = __fsub_rn(r_m[tok][d + 0], cv4.x);
        r_m[tok][d + 1] = __fsub_rn(r_m[tok][d + 1], cv4.y);
        r_m[tok][d + 2] = __fsub_rn(r_m[tok][d + 2], cv4.z);
        r_m[tok][d + 3] = __fsub_rn(r_m[tok][d + 3], cv4.w);
      }
    }
    __syncthreads();  // r stable before next level's A
  }

  // ---- straight_through = fl(l + fl(q - l)), q = fl(l - r) ----
  {
    int tok = tid >> 4;
    int db = (tid & 15) * 16;
#pragma unroll
    for (int j = 0; j < 4; ++j) {
      int d = db + j * 4;
      size_t gi = (size_t)(n0 + tok) * DIM + d;
      float4 l4 = *(const float4*)(latent + gi);
      float4 qv;
      float q;
      q = __fsub_rn(l4.x, r_m[tok][d + 0]);
      qv.x = __fadd_rn(l4.x, __fsub_rn(q, l4.x));
      q = __fsub_rn(l4.y, r_m[tok][d + 1]);
      qv.y = __fadd_rn(l4.y, __fsub_rn(q, l4.y));
      q = __fsub_rn(l4.z, r_m[tok][d + 2]);
      qv.z = __fadd_rn(l4.z, __fsub_rn(q, l4.z));
      q = __fsub_rn(l4.w, r_m[tok][d + 3]);
      qv.w = __fadd_rn(l4.w, __fsub_rn(q, l4.w));
      *(float4*)(out + gi) = qv;
    }
  }
}

extern "C" void kernel_launch(void* const* d_in, const int* in_sizes, int n_in,
                              void* d_out, int out_size, void* d_ws,
                              size_t ws_size, hipStream_t stream) {
  const float* latent = (const float*)d_in[0];
  const float* codebooks = (const float*)d_in[1];
  float* out = (float*)d_out;
  float* C32g = (float*)d_ws;  // 8192 floats

  hipLaunchKernelGGL(c2_kernel, dim3(DEPTH * KCB / 256), dim3(256), 0, stream,
                     codebooks, C32g);
  hipLaunchKernelGGL(rvq_kernel, dim3(NTOK / TM), dim3(512), 0, stream, latent,
                     codebooks, C32g, out);
}

// Round 9
// 10761.647 us; speedup vs baseline: 2.2894x; 1.0078x over previous
//
#include <hip/hip_runtime.h>

// Residual VQ — np-f32 bit-faithful. Round 9: get VGPR under the 4-waves/SIMD
// cliff. Evidence: at LDS=68.6KB, VGPR=64 -> 2 blocks/CU (occ 45.6%) but
// VGPR=128 -> 1 block (occ 24.3%): usable VGPR/lane/SIMD < 512, so 128 regs
// cannot co-schedule two 8-wave blocks. Fix: drop the cv[8] preload (saves
// ~24 regs) -> target <=116 VGPR. Scheduling-only change; every acc[i][j]
// keeps its own strictly d-ascending fmaf chain -> decisions bit-identical.
//
// Frozen numerics (validated rounds 4/6/8):
//   dot:   single sequential fmaf chain over d=0..255 ascending per (tok,k)
//   A,C:   np pairwise-sum-of-squares (AVX512 tree) replica
//   dist:  fl(fl(A - fl(2*dot)) + C), argmin strict-<, first-index ties
//   resid: r = fl(r - c[idx]) elementwise
//
// Org: block = 32 tokens, 512 threads = 8 waves. Wave w owns k in
// [128w, 128w+128). Lane grid 4 tg x 16 kg; per lane 8 tokens (tg+4i) x
// 8 k (128w+kg+16j), acc[8][8] persists over 32 d-slices of 8.
// LDS (~68 KB): r_m[32][260] row-major, c_s[1024*8] with float4-slot
// swizzle part ^ ((k>>2)&1).

#define NTOK 131072
#define DEPTH 8
#define KCB 1024
#define DIM 256
#define TM 32
#define DS 8
#define NSLICE (DIM / DS)
#define RP 260

__device__ __forceinline__ float np_sumsq_128(const float* p) {
  float s[16];
#pragma unroll
  for (int l = 0; l < 16; ++l) {
    float r0 = __fadd_rn(__fmul_rn(p[l], p[l]),
                         __fmul_rn(p[l + 64], p[l + 64]));
    float r1 = __fadd_rn(__fmul_rn(p[l + 16], p[l + 16]),
                         __fmul_rn(p[l + 80], p[l + 80]));
    float r2 = __fadd_rn(__fmul_rn(p[l + 32], p[l + 32]),
                         __fmul_rn(p[l + 96], p[l + 96]));
    float r3 = __fadd_rn(__fmul_rn(p[l + 48], p[l + 48]),
                         __fmul_rn(p[l + 112], p[l + 112]));
    s[l] = __fadd_rn(__fadd_rn(r0, r1), __fadd_rn(r2, r3));
  }
  float t[8];
#pragma unroll
  for (int l = 0; l < 8; ++l) t[l] = __fadd_rn(s[l], s[l + 8]);
  float u[4];
#pragma unroll
  for (int l = 0; l < 4; ++l) u[l] = __fadd_rn(t[l], t[l + 4]);
  return __fadd_rn(__fadd_rn(u[0], u[2]), __fadd_rn(u[1], u[3]));
}

__device__ __forceinline__ float np_sumsq_256(const float* p) {
  return __fadd_rn(np_sumsq_128(p), np_sumsq_128(p + 128));
}

__global__ __launch_bounds__(256) void c2_kernel(const float* __restrict__ cbs,
                                                 float* __restrict__ C32g) {
  int gid = blockIdx.x * 256 + threadIdx.x;
  C32g[gid] = np_sumsq_256(cbs + (size_t)gid * DIM);
}

__global__ __launch_bounds__(512, 2) void rvq_kernel(
    const float* __restrict__ latent, const float* __restrict__ cbs,
    const float* __restrict__ C32g, float* __restrict__ out) {
  __shared__ float r_m[TM][RP];
  __shared__ float c_s[KCB * DS];
  __shared__ float A_s[TM];
  __shared__ float best_s[8][TM];
  __shared__ int bidx_s[8][TM];
  __shared__ int idx_s[TM];

  const int tid = threadIdx.x;
  const int w = tid >> 6;
  const int lane = tid & 63;
  const int tg = lane >> 4;
  const int kg = lane & 15;
  const int n0 = blockIdx.x * TM;

  // ---- stage latent -> r_m (exact copy) ----
  {
    int tok = tid >> 4;
    int db = (tid & 15) * 16;
    const float* src = latent + (size_t)(n0 + tok) * DIM + db;
#pragma unroll
    for (int j = 0; j < 4; ++j)
      *(float4*)&r_m[tok][db + j * 4] = *(const float4*)(src + j * 4);
  }
  __syncthreads();

  const int kbase = w * 128 + kg;   // lane's k_j = kbase + 16*j
  const int swz = (kbase >> 2) & 1; // j-invariant ((16j)>>2 is even)

  for (int lvl = 0; lvl < DEPTH; ++lvl) {
    const float* cb = cbs + (size_t)lvl * KCB * DIM;
    if (tid < TM) A_s[tid] = np_sumsq_256(&r_m[tid][0]);

    float acc[8][8];
#pragma unroll
    for (int i = 0; i < 8; ++i)
#pragma unroll
      for (int j = 0; j < 8; ++j) acc[i][j] = 0.f;

    for (int ds = 0; ds < NSLICE; ++ds) {
      __syncthreads();  // prev slice reads done (and A_s ordered at ds=0)
      // ---- stage c-slice [1024 k][8 d]: 2048 float4 slots / 512 thr = 4 ----
      {
        const int d0 = ds * DS;
        const int part = tid & 1;
#pragma unroll
        for (int g = 0; g < 4; ++g) {
          int k = g * 256 + (tid >> 1);
          float4 v = *(const float4*)(cb + (size_t)k * DIM + d0 + part * 4);
          int p2 = part ^ ((k >> 2) & 1);
          *(float4*)&c_s[k * 8 + p2 * 4] = v;
        }
      }
      __syncthreads();

      // ---- 2 substeps of 4 d-values each; chain strictly d-ascending ----
      // cv read per-j (not preloaded): ~24 fewer live VGPRs.
#pragma unroll
      for (int sub = 0; sub < 2; ++sub) {
        float4 rv[8];
        const int rd = ds * DS + sub * 4;
#pragma unroll
        for (int i = 0; i < 8; ++i)
          rv[i] = *(const float4*)&r_m[tg + 4 * i][rd];
        const int csub = (sub ^ swz) << 2;
#pragma unroll
        for (int j = 0; j < 8; ++j) {
          const float4 cv = *(const float4*)&c_s[(kbase + 16 * j) * 8 + csub];
#pragma unroll
          for (int i = 0; i < 8; ++i) {
            float a = acc[i][j];
            a = fmaf(rv[i].x, cv.x, a);
            a = fmaf(rv[i].y, cv.y, a);
            a = fmaf(rv[i].z, cv.z, a);
            a = fmaf(rv[i].w, cv.w, a);
            acc[i][j] = a;
          }
        }
      }
    }

    // ---- dist combine + per-lane argmin (j ascending = k ascending) ----
    float bv[8];
    int bk[8];
#pragma unroll
    for (int i = 0; i < 8; ++i) {
      bv[i] = 3.4e38f;
      bk[i] = 0;
    }
#pragma unroll
    for (int j = 0; j < 8; ++j) {
      const int k = kbase + 16 * j;
      const float C = C32g[lvl * KCB + k];
#pragma unroll
      for (int i = 0; i < 8; ++i) {
        float d = __fadd_rn(
            __fsub_rn(A_s[tg + 4 * i], __fmul_rn(2.0f, acc[i][j])), C);
        if (d < bv[i]) {
          bv[i] = d;
          bk[i] = k;
        }
      }
    }

    // ---- butterfly over the 16 kg lanes (index tie-break) ----
#pragma unroll
    for (int m = 1; m <= 8; m <<= 1) {
#pragma unroll
      for (int i = 0; i < 8; ++i) {
        float ov = __shfl_xor(bv[i], m);
        int ok = __shfl_xor(bk[i], m);
        if (ov < bv[i] || (ov == bv[i] && ok < bk[i])) {
          bv[i] = ov;
          bk[i] = ok;
        }
      }
    }
    if (kg == 0) {
#pragma unroll
      for (int i = 0; i < 8; ++i) {
        best_s[w][tg + 4 * i] = bv[i];
        bidx_s[w][tg + 4 * i] = bk[i];
      }
    }
    __syncthreads();

    // ---- cross-wave merge (w ascending = k ascending; strict <) ----
    if (tid < TM) {
      float b = best_s[0][tid];
      int k = bidx_s[0][tid];
#pragma unroll
      for (int ww = 1; ww < 8; ++ww) {
        float ov = best_s[ww][tid];
        int ok = bidx_s[ww][tid];
        if (ov < b || (ov == b && ok < k)) {
          b = ov;
          k = ok;
        }
      }
      idx_s[tid] = k;
      out[(size_t)NTOK * DIM + (size_t)lvl * NTOK + n0 + tid] = (float)k;
    }
    __syncthreads();

    // ---- residual update: r = fl(r - c[idx]) elementwise ----
    {
      int tok = tid >> 4;
      int db = (tid & 15) * 16;
      const float* crow = cb + (size_t)idx_s[tok] * DIM + db;
#pragma unroll
      for (int j = 0; j < 4; ++j) {
        float4 cv4 = *(const float4*)(crow + j * 4);
        int d = db + j * 4;
        r_m[tok][d + 0] = __fsub_rn(r_m[tok][d + 0], cv4.x);
        r_m[tok][d + 1] = __fsub_rn(r_m[tok][d + 1], cv4.y);
        r_m[tok][d + 2] = __fsub_rn(r_m[tok][d + 2], cv4.z);
        r_m[tok][d + 3] = __fsub_rn(r_m[tok][d + 3], cv4.w);
      }
    }
    __syncthreads();  // r stable before next level's A
  }

  // ---- straight_through = fl(l + fl(q - l)), q = fl(l - r) ----
  {
    int tok = tid >> 4;
    int db = (tid & 15) * 16;
#pragma unroll
    for (int j = 0; j < 4; ++j) {
      int d = db + j * 4;
      size_t gi = (size_t)(n0 + tok) * DIM + d;
      float4 l4 = *(const float4*)(latent + gi);
      float4 qv;
      float q;
      q = __fsub_rn(l4.x, r_m[tok][d + 0]);
      qv.x = __fadd_rn(l4.x, __fsub_rn(q, l4.x));
      q = __fsub_rn(l4.y, r_m[tok][d + 1]);
      qv.y = __fadd_rn(l4.y, __fsub_rn(q, l4.y));
      q = __fsub_rn(l4.z, r_m[tok][d + 2]);
      qv.z = __fadd_rn(l4.z, __fsub_rn(q, l4.z));
      q = __fsub_rn(l4.w, r_m[tok][d + 3]);
      qv.w = __fadd_rn(l4.w, __fsub_rn(q, l4.w));
      *(float4*)(out + gi) = qv;
    }
  }
}

extern "C" void kernel_launch(void* const* d_in, const int* in_sizes, int n_in,
                              void* d_out, int out_size, void* d_ws,
                              size_t ws_size, hipStream_t stream) {
  const float* latent = (const float*)d_in[0];
  const float* codebooks = (const float*)d_in[1];
  float* out = (float*)d_out;
  float* C32g = (float*)d_ws;  // 8192 floats

  hipLaunchKernelGGL(c2_kernel, dim3(DEPTH * KCB / 256), dim3(256), 0, stream,
                     codebooks, C32g);
  hipLaunchKernelGGL(rvq_kernel, dim3(NTOK / TM), dim3(512), 0, stream, latent,
                     codebooks, C32g, out);
}